// Round 9
// baseline (353.983 us; speedup 1.0000x reference)
//
#include <hip/hip_runtime.h>
#include <math.h>

// Problem constants (fixed by the reference setup_inputs):
//   N=8192 nodes, L=512 words/node, H=64 hidden, V=50000 vocab, steps = N-1
#define NODES  8192
#define STEPS  8191
#define LW     512
#define H      64
#define VOCAB  50000
#define SPIN_LIMIT 50000   // legit worst wait ~50us; this is ~12ms -> fail loud

// ---------------------------------------------------------------------------
__global__ void ws_too_small_kernel(float* __restrict__ out) {
    if (threadIdx.x < H) out[threadIdx.x] = -12345.0f;
}

// ---------------------------------------------------------------------------
// embedding fp32 -> bf16 (RNE). 6250 blocks x 256 thr x 2 elems = 3.2M.
// ---------------------------------------------------------------------------
__global__ __launch_bounds__(256)
void cvt_emb(const float* __restrict__ emb, unsigned int* __restrict__ embh) {
    int i = blockIdx.x * 256 + threadIdx.x;            // over float2s
    float2 v = reinterpret_cast<const float2*>(emb)[i];
    unsigned int ux = __float_as_uint(v.x);
    unsigned int uy = __float_as_uint(v.y);
    unsigned int bx = (ux + 0x7fffu + ((ux >> 16) & 1u)) >> 16;
    unsigned int by = (uy + 0x7fffu + ((uy >> 16) & 1u)) >> 16;
    embh[i] = bx | (by << 16);
}

// ---------------------------------------------------------------------------
// Zero count/cursor/flag/counter (24832 ints; ws poisoned every call).
// ---------------------------------------------------------------------------
__global__ __launch_bounds__(256)
void zero_kernel(int* __restrict__ p) {
    p[blockIdx.x * blockDim.x + threadIdx.x] = 0;
}

__global__ __launch_bounds__(256)
void hist_writers(const int* __restrict__ tree, int* __restrict__ count) {
    int j = blockIdx.x * blockDim.x + threadIdx.x;
    if (j < STEPS) atomicAdd(&count[tree[2 * j + 1]], 1);
}

// ---------------------------------------------------------------------------
// Exclusive prefix sum over 8192 ints, single block of 1024 threads.
// ---------------------------------------------------------------------------
__global__ __launch_bounds__(1024)
void prefix_kernel(const int* __restrict__ cnt, int* __restrict__ off) {
    __shared__ int wsum[16];
    int tid  = threadIdx.x;
    int lane = tid & 63;
    int wv   = tid >> 6;
    int base = tid * 8;

    int v[8], run = 0;
    #pragma unroll
    for (int e = 0; e < 8; ++e) { v[e] = run; run += cnt[base + e]; }

    int x = run;
    #pragma unroll
    for (int d = 1; d < 64; d <<= 1) {
        int y = __shfl_up(x, d, 64);
        if (lane >= d) x += y;
    }
    if (lane == 63) wsum[wv] = x;
    __syncthreads();
    if (wv == 0) {
        int s = (lane < 16) ? wsum[lane] : 0;
        #pragma unroll
        for (int d = 1; d < 16; d <<= 1) {
            int y = __shfl_up(s, d, 64);
            if (lane >= d) s += y;
        }
        if (lane < 16) wsum[lane] = s;
    }
    __syncthreads();
    int wbase = (wv > 0) ? wsum[wv - 1] : 0;
    int tbase = wbase + x - run;
    #pragma unroll
    for (int e = 0; e < 8; ++e) off[base + e] = tbase + v[e];
    if (tid == 1023) off[8192] = tbase + run;
}

__global__ __launch_bounds__(256)
void scatter_writers(const int* __restrict__ tree, const int* __restrict__ woff,
                     int* __restrict__ cursor, int* __restrict__ writers) {
    int j = blockIdx.x * blockDim.x + threadIdx.x;
    if (j >= STEPS) return;
    int v = tree[2 * j + 1];
    int pos = atomicAdd(&cursor[v], 1);
    writers[woff[v] + pos] = j;
}

__global__ __launch_bounds__(256)
void pred_bucket(const int* __restrict__ tree, const int* __restrict__ woff,
                 const int* __restrict__ writers, int* __restrict__ pred) {
    int i = blockIdx.x * blockDim.x + threadIdx.x;
    if (i >= STEPS) return;
    int v  = tree[2 * i];
    int t0 = woff[v], t1 = woff[v + 1];
    int best = -1;
    for (int t = t0; t < t1; ++t) {
        int j = writers[t];
        if (j < i && j > best) best = j;
    }
    pred[i] = best;
}

// ---------------------------------------------------------------------------
// gather (bf16 table, fp32 accumulate) + W projection + root fusion.
// Roots (pred<0): h = (1-hsig(az))*tanh(ah) -> child_h, and flag[i]=1
// (plain stores; kernel-boundary release makes them coherent for flow_scan).
// unroll 8: double the gather loads in flight (latency-vs-BW experiment).
// ---------------------------------------------------------------------------
__global__ __launch_bounds__(256)
void gather_project(const float* __restrict__ xw, const int* __restrict__ xi,
                    const unsigned short* __restrict__ embh,
                    const float* __restrict__ Wz, const float* __restrict__ Wr,
                    const float* __restrict__ Wh,
                    const float* __restrict__ bz, const float* __restrict__ br,
                    const float* __restrict__ bh,
                    const int* __restrict__ pred,
                    float* __restrict__ A, float* __restrict__ child_h,
                    int* __restrict__ flag) {
    int i    = blockIdx.x;
    int tid  = threadIdx.x;
    int wave = tid >> 6;
    int lane = tid & 63;
    int g8   = lane >> 3;             // row-group 0..7 within wave
    int h8   = (lane & 7) * 8;        // h offset (8 bf16 = 16 B)

    __shared__ float part[4][64];
    __shared__ float xe[64];

    const float* xwi = xw + (size_t)i * LW;
    const int*   xii = xi + (size_t)i * LW;

    float acc[8] = {0.f, 0.f, 0.f, 0.f, 0.f, 0.f, 0.f, 0.f};
    #pragma unroll 8
    for (int it = 0; it < 16; ++it) {
        int l   = wave * 128 + it * 8 + g8;
        int idx = xii[l];
        float w = xwi[l];
        uint4 q = *reinterpret_cast<const uint4*>(embh + ((size_t)idx << 6) + h8);
        acc[0] = fmaf(w, __uint_as_float(q.x << 16),          acc[0]);
        acc[1] = fmaf(w, __uint_as_float(q.x & 0xffff0000u),  acc[1]);
        acc[2] = fmaf(w, __uint_as_float(q.y << 16),          acc[2]);
        acc[3] = fmaf(w, __uint_as_float(q.y & 0xffff0000u),  acc[3]);
        acc[4] = fmaf(w, __uint_as_float(q.z << 16),          acc[4]);
        acc[5] = fmaf(w, __uint_as_float(q.z & 0xffff0000u),  acc[5]);
        acc[6] = fmaf(w, __uint_as_float(q.w << 16),          acc[6]);
        acc[7] = fmaf(w, __uint_as_float(q.w & 0xffff0000u),  acc[7]);
    }
    // reduce the 8 row-groups (lanes differing in bits 3..5)
    #pragma unroll
    for (int c = 0; c < 8; ++c) {
        acc[c] += __shfl_xor(acc[c], 8,  64);
        acc[c] += __shfl_xor(acc[c], 16, 64);
        acc[c] += __shfl_xor(acc[c], 32, 64);
    }
    if (lane < 8) {
        #pragma unroll
        for (int c = 0; c < 8; ++c) part[wave][lane * 8 + c] = acc[c];
    }
    __syncthreads();
    if (tid < 64) xe[tid] = part[0][tid] + part[1][tid] + part[2][tid] + part[3][tid];
    __syncthreads();

    float s = 0.f;
    if (tid < 192) {
        int o = tid & 63;
        const float* W = (tid < 64) ? Wz : (tid < 128 ? Wr : Wh);
        const float* b = (tid < 64) ? bz : (tid < 128 ? br : bh);
        s = b[o];
        #pragma unroll
        for (int j = 0; j < H; j += 4) {
            float4 w4 = *reinterpret_cast<const float4*>(W + (size_t)o * H + j);
            s = fmaf(w4.x, xe[j],     s);
            s = fmaf(w4.y, xe[j + 1], s);
            s = fmaf(w4.z, xe[j + 2], s);
            s = fmaf(w4.w, xe[j + 3], s);
        }
    }
    bool isroot = (pred[i] < 0);       // block-uniform
    if (tid < 64)                part[0][tid]       = s;   // az
    if (tid >= 128 && tid < 192) part[1][tid - 128] = s;   // ah
    __syncthreads();
    if (isroot) {
        if (tid < 64) {
            float z = fminf(fmaxf(0.2f * part[0][tid] + 0.5f, 0.f), 1.f);
            float c = tanhf(part[1][tid]);
            child_h[(size_t)i * H + tid] = (1.f - z) * c;
        }
        if (tid == 64) flag[i] = 1;
    } else {
        if (tid < 192) A[(size_t)i * 192 + tid] = s;
    }
}

// ---------------------------------------------------------------------------
// Dataflow scan: ONE kernel for all non-root steps.
// 256 blocks x 256 thr = 1024 waves (co-resident: 1 block/CU). Waves draw
// ascending step tickets; pred(i) < i makes index order topological ->
// every producer ticket is held by a running wave -> deadlock-free.
// Coherence protocol (cross-XCD safe):
//   producer: agent-scope atomic stores of h (write-through past local L2)
//             -> __threadfence -> atomicExch(flag)
//   consumer: atomic poll of flag (coherent point) -> __threadfence ->
//             plain ph load (consumer L2 provably holds no pre-flag copy:
//             kernel-start invalidate + 256B rows = no line sharing).
// Spin is BOUNDED: a protocol failure gives a visible absmax, never a hang.
// ---------------------------------------------------------------------------
__global__ __launch_bounds__(256)
void flow_scan(const float* __restrict__ A, const int* __restrict__ pred,
               const float* __restrict__ Uz, const float* __restrict__ Ur,
               const float* __restrict__ Uh,
               int* __restrict__ flag, int* __restrict__ counter,
               float* __restrict__ child_h) {
    int lane = threadIdx.x & 63;

    float uz[H], ur[H], uh[H];
    #pragma unroll
    for (int j = 0; j < H; j += 4) {
        float4 a4 = *reinterpret_cast<const float4*>(Uz + (size_t)lane * H + j);
        uz[j] = a4.x; uz[j+1] = a4.y; uz[j+2] = a4.z; uz[j+3] = a4.w;
        float4 b4 = *reinterpret_cast<const float4*>(Ur + (size_t)lane * H + j);
        ur[j] = b4.x; ur[j+1] = b4.y; ur[j+2] = b4.z; ur[j+3] = b4.w;
        float4 c4 = *reinterpret_cast<const float4*>(Uh + (size_t)lane * H + j);
        uh[j] = c4.x; uh[j+1] = c4.y; uh[j+2] = c4.z; uh[j+3] = c4.w;
    }

    while (true) {
        int t = 0;
        if (lane == 0) t = atomicAdd(counter, 1);
        int i = __builtin_amdgcn_readfirstlane(t);
        if (i >= STEPS) break;

        int p = pred[i];                        // wave-uniform
        if (p < 0) continue;                    // root: done by gather

        // prefetch A (independent of the flag wait)
        const float* Ai = A + (size_t)i * 192;
        float az = Ai[lane];
        float ar = Ai[64 + lane];
        float ah = Ai[128 + lane];

        // wait for producer (lane 0 polls the coherent point)
        int done = 0, spins = 0;
        while (!done) {
            int f = 0;
            if (lane == 0) f = atomicAdd(&flag[p], 0);
            done = __builtin_amdgcn_readfirstlane(f);
            if (!done) {
                __builtin_amdgcn_s_sleep(1);
                if (++spins > SPIN_LIMIT) break; // fail loud, not hung
            }
        }
        __threadfence();
        float ph = child_h[(size_t)p * H + lane];

        #pragma unroll
        for (int j = 0; j < H; ++j) {
            float s = __shfl(ph, j, 64);
            az = fmaf(uz[j], s, az);
            ar = fmaf(ur[j], s, ar);
        }
        float z = fminf(fmaxf(0.2f * az + 0.5f, 0.f), 1.f);
        float r = fminf(fmaxf(0.2f * ar + 0.5f, 0.f), 1.f);
        float phr = ph * r;
        #pragma unroll
        for (int j = 0; j < H; ++j) {
            float s = __shfl(phr, j, 64);
            ah = fmaf(uh[j], s, ah);
        }
        float c    = tanhf(ah);
        float hval = z * ph + (1.f - z) * c;

        // write-through past local L2 so the LLC is the source of truth
        __hip_atomic_store(&child_h[(size_t)i * H + lane], hval,
                           __ATOMIC_RELAXED, __HIP_MEMORY_SCOPE_AGENT);
        __threadfence();
        if (lane == 0) atomicExch(&flag[i], 1);
    }
}

// ---------------------------------------------------------------------------
// out[h] = max over steps i in [num_parent-1, STEPS) of child_h[i,h]
// ---------------------------------------------------------------------------
__global__ __launch_bounds__(256)
void reduce_partial(const float* __restrict__ child_h,
                    const int* __restrict__ np_ptr,
                    float* __restrict__ partial) {
    int b   = blockIdx.x;
    int tid = threadIdx.x;
    int h   = tid & 63;
    int grp = tid >> 6;
    int np    = *np_ptr;
    int start = np - 1;
    int total = STEPS - start;
    int per   = (total + gridDim.x - 1) / gridDim.x;
    int r0 = start + b * per;
    int r1 = r0 + per; if (r1 > STEPS) r1 = STEPS;
    float m = -INFINITY;
    for (int row = r0 + grp; row < r1; row += 4)
        m = fmaxf(m, child_h[(size_t)row * H + h]);
    __shared__ float sm[4][64];
    sm[grp][h] = m;
    __syncthreads();
    if (tid < 64)
        partial[b * 64 + tid] = fmaxf(fmaxf(sm[0][tid], sm[1][tid]),
                                      fmaxf(sm[2][tid], sm[3][tid]));
}

__global__ void reduce_final(const float* __restrict__ partial,
                             float* __restrict__ out, int nb) {
    int h = threadIdx.x;
    float m = -INFINITY;
    for (int b = 0; b < nb; ++b) m = fmaxf(m, partial[b * 64 + h]);
    out[h] = m;
}

// ---------------------------------------------------------------------------
extern "C" void kernel_launch(void* const* d_in, const int* in_sizes, int n_in,
                              void* d_out, int out_size, void* d_ws, size_t ws_size,
                              hipStream_t stream) {
    const float* xw   = (const float*)d_in[0];
    const int*   xi   = (const int*)  d_in[1];
    const int*   tree = (const int*)  d_in[2];
    const int*   np   = (const int*)  d_in[3];
    const float* emb  = (const float*)d_in[4];
    const float* Wz   = (const float*)d_in[5];
    const float* Uz   = (const float*)d_in[6];
    const float* bz   = (const float*)d_in[7];
    const float* Wr   = (const float*)d_in[8];
    const float* Ur   = (const float*)d_in[9];
    const float* br   = (const float*)d_in[10];
    const float* Wh   = (const float*)d_in[11];
    const float* Uh   = (const float*)d_in[12];
    const float* bh   = (const float*)d_in[13];

    // ---- workspace layout ----
    size_t bA   = (size_t)STEPS * 192 * 4;        // A        6,290,688 B
    size_t bCH  = (size_t)STEPS * H   * 4;        // child_h  2,096,896 B
    size_t bEH  = (size_t)VOCAB * H   * 2;        // embh     6,400,000 B
    // ints: pred[8192], writers[8192], woff[8256],
    //       zblock: count[8192], cursor[8192], flag[8192], counter[256]
    size_t nInt = 8192 * 2 + 8256 + (8192 * 3 + 256);
    size_t bPar = 56 * 64 * 4 + 256;
    size_t need = bA + bCH + bEH + nInt * 4 + bPar;
    if (ws_size < need) {
        ws_too_small_kernel<<<1, 64, 0, stream>>>((float*)d_out);
        return;
    }

    char* base = (char*)d_ws;
    float*          A       = (float*)base;                 base += bA;
    float*          child_h = (float*)base;                 base += bCH;
    unsigned short* embh    = (unsigned short*)base;        base += bEH;
    int*            pred    = (int*)base;                   // [8192]
    int*            writers = pred    + 8192;               // [8192]
    int*            woff    = writers + 8192;               // [8256]
    int*            zblock  = woff    + 8256;               // 24832 ints
    int*            count   = zblock;                       // [8192]
    int*            cursor  = count   + 8192;               // [8192]
    int*            flag    = cursor  + 8192;               // [8192]
    int*            counter = flag    + 8192;               // [1] (+255 pad)
    float*          partial = (float*)(counter + 256);      // [56,64]

    // embedding -> bf16 (independent)
    cvt_emb        <<<6250, 256, 0, stream>>>(emb, (unsigned int*)embh);

    // zero count/cursor/flag/counter  (24832 ints = 97 * 256)
    zero_kernel    <<<97,  256, 0, stream>>>(zblock);

    // pred via bucketing
    hist_writers   <<<32,  256, 0, stream>>>(tree, count);
    prefix_kernel  <<<1,  1024, 0, stream>>>(count, woff);
    scatter_writers<<<32,  256, 0, stream>>>(tree, woff, cursor, writers);
    pred_bucket    <<<32,  256, 0, stream>>>(tree, woff, writers, pred);

    // gather + projection + root steps (sets root flags)
    gather_project <<<STEPS, 256, 0, stream>>>(xw, xi, embh, Wz, Wr, Wh,
                                               bz, br, bh, pred, A, child_h,
                                               flag);

    // whole recurrence in one dataflow kernel
    flow_scan      <<<256, 256, 0, stream>>>(A, pred, Uz, Ur, Uh,
                                             flag, counter, child_h);

    reduce_partial <<<56,  256, 0, stream>>>(child_h, np, partial);
    reduce_final   <<<1,    64, 0, stream>>>(partial, (float*)d_out, 56);
}